// Round 1
// baseline (4442.484 us; speedup 1.0000x reference)
//
#include <hip/hip_runtime.h>
#include <cmath>

namespace {
constexpr int B = 8;
constexpr int T = 2048;
constexpr int D = 512;
constexpr int S = 2048;
constexpr int R = 64;
constexpr int KTOP = 16;
constexpr int NT = 4;   // tokens per block in write kernel
constexpr int NR = 16;  // rows per block in qk kernel
constexpr int NI = 4;   // slots per block in prop kernel

__device__ __forceinline__ float signf(float v) {
    return (v > 0.f) ? 1.f : ((v < 0.f) ? -1.f : 0.f);
}
} // namespace

// ---------- state init: state_ws[b][s] = sign * softmax(|init_state|) ----------
__global__ void k_init_state(const float* __restrict__ init_state,
                             float* __restrict__ state_ws) {
    int b = blockIdx.x;
    int tid = threadIdx.x;
    __shared__ float red[256];
    float m = -1e30f;
    for (int s = tid; s < S; s += 256) m = fmaxf(m, fabsf(init_state[s]));
    red[tid] = m; __syncthreads();
    for (int off = 128; off > 0; off >>= 1) {
        if (tid < off) red[tid] = fmaxf(red[tid], red[tid + off]);
        __syncthreads();
    }
    m = red[0]; __syncthreads();
    float sum = 0.f;
    for (int s = tid; s < S; s += 256) sum += expf(fabsf(init_state[s]) - m);
    red[tid] = sum; __syncthreads();
    for (int off = 128; off > 0; off >>= 1) {
        if (tid < off) red[tid] += red[tid + off];
        __syncthreads();
    }
    float inv = 1.0f / red[0];
    for (int s = tid; s < S; s += 256) {
        float v = init_state[s];
        state_ws[(size_t)b * S + s] = signf(v) * expf(fabsf(v) - m) * inv;
    }
}

// ---------- val init: val1[b][s][:] = unit_norm(init_val[s]) ----------
__global__ void k_init_val(const float* __restrict__ init_val,
                           float* __restrict__ val1) {
    int wave = threadIdx.x >> 6;
    int lane = threadIdx.x & 63;
    int row = blockIdx.x * 4 + wave;        // row = b*S + s
    int s = row & (S - 1);
    const float* src = init_val + (size_t)s * D;
    float vals[8];
    float ss = 0.f;
#pragma unroll
    for (int i = 0; i < 8; i++) {
        float v = src[lane + 64 * i];
        vals[i] = v;
        ss += v * v;
    }
#pragma unroll
    for (int off = 32; off > 0; off >>= 1) ss += __shfl_xor(ss, off, 64);
    float scale = 1.0f / (sqrtf(ss) + 1e-6f);
    float* dst = val1 + (size_t)row * D;
#pragma unroll
    for (int i = 0; i < 8; i++) dst[lane + 64 * i] = vals[i] * scale;
}

// ---------- write stage: route scores -> topk -> scatter ----------
__global__ void __launch_bounds__(256) k_write(const float* __restrict__ x,
                                               const float* __restrict__ route_a,
                                               const float* __restrict__ route_b,
                                               float* __restrict__ val1,
                                               float* __restrict__ state_ws) {
    __shared__ float xs[NT][D];     // raw x rows (8 KB)
    __shared__ float sc[NT][S];     // scores (32 KB)
    __shared__ float xr[NT][R];     // x . route_a (1 KB)
    __shared__ float red[256];
    __shared__ int   redi[256];
    __shared__ float xinv[NT];
    __shared__ float gval[KTOP];
    __shared__ int   gidx[KTOP];
    __shared__ float wgt[KTOP];
    __shared__ float spv[KTOP];

    int tid = threadIdx.x;
    int tb = blockIdx.x * NT;       // token base; all NT tokens share b
    int b = tb / T;

    // load x rows
    for (int tt = 0; tt < NT; tt++) {
        const float* xp = x + (size_t)(tb + tt) * D;
        for (int d = tid; d < D; d += 256) xs[tt][d] = xp[d];
    }
    __syncthreads();

    // x norms
    for (int tt = 0; tt < NT; tt++) {
        float ssum = 0.f;
        for (int d = tid; d < D; d += 256) { float v = xs[tt][d]; ssum += v * v; }
        red[tid] = ssum; __syncthreads();
        for (int off = 128; off > 0; off >>= 1) {
            if (tid < off) red[tid] += red[tid + off];
            __syncthreads();
        }
        if (tid == 0) xinv[tt] = 1.0f / (sqrtf(red[0]) + 1e-6f);
        __syncthreads();
    }

    // xr = x . route_a  (r = tid%64, grp = tid/64 covers 128 d's)
    {
        int r = tid & 63, grp = tid >> 6;
        float acc[NT] = {0.f, 0.f, 0.f, 0.f};
        for (int d = grp * 128; d < grp * 128 + 128; d++) {
            float a = route_a[(size_t)d * R + r];
#pragma unroll
            for (int tt = 0; tt < NT; tt++) acc[tt] += xs[tt][d] * a;
        }
        for (int tt = 0; tt < NT; tt++) {
            red[tid] = acc[tt]; __syncthreads();
            if (tid < 64)
                xr[tt][tid] = red[tid] + red[tid + 64] + red[tid + 128] + red[tid + 192];
            __syncthreads();
        }
    }

    // scores = xr . route_b
    for (int i = 0; i < S / 256; i++) {
        int s = tid + 256 * i;
        float acc[NT] = {0.f, 0.f, 0.f, 0.f};
        for (int r = 0; r < R; r++) {
            float bv = route_b[(size_t)r * S + s];
#pragma unroll
            for (int tt = 0; tt < NT; tt++) acc[tt] += xr[tt][r] * bv;
        }
        for (int tt = 0; tt < NT; tt++) sc[tt][s] = acc[tt];
    }
    __syncthreads();

    int lane = tid & 63, wv = tid >> 6;
    for (int tt = 0; tt < NT; tt++) {
        // top-16 by |score| (iterative argmax; winner zeroed)
        for (int k = 0; k < KTOP; k++) {
            float bestv = -1.f; int besti = 0;
            for (int i = 0; i < S / 256; i++) {
                int s = tid + 256 * i;
                float a = fabsf(sc[tt][s]);
                if (a > bestv) { bestv = a; besti = s; }
            }
#pragma unroll
            for (int off = 32; off > 0; off >>= 1) {
                float ov = __shfl_xor(bestv, off, 64);
                int   oi = __shfl_xor(besti, off, 64);
                if (ov > bestv || (ov == bestv && oi < besti)) { bestv = ov; besti = oi; }
            }
            if (lane == 0) { red[wv] = bestv; redi[wv] = besti; }
            __syncthreads();
            if (tid == 0) {
                float bv = red[0]; int bi = redi[0];
                for (int w2 = 1; w2 < 4; w2++) {
                    if (red[w2] > bv || (red[w2] == bv && redi[w2] < bi)) {
                        bv = red[w2]; bi = redi[w2];
                    }
                }
                gval[k] = sc[tt][bi]; gidx[k] = bi;
                sc[tt][bi] = 0.0f;
            }
            __syncthreads();
        }
        // signed-abs-softmax over the 16 gathered scores + softplus
        if (tid == 0) {
            float m = fabsf(gval[0]);   // descending abs order => first is max
            float e[KTOP];
            float sum = 0.f;
            for (int k = 0; k < KTOP; k++) { e[k] = expf(fabsf(gval[k]) - m); sum += e[k]; }
            float inv = 1.0f / sum;
            for (int k = 0; k < KTOP; k++) {
                float g = gval[k];
                wgt[k] = signf(g) * e[k] * inv;
                spv[k] = (g > 20.f) ? g : log1pf(expf(g));
            }
        }
        __syncthreads();
        // scatter w * x/||x|| into val1, softplus(g) into state
        float xi = xinv[tt];
        for (int k = 0; k < KTOP; k++) {
            int slot = gidx[k];
            float c = wgt[k] * xi;
            float* dst = val1 + ((size_t)b * S + slot) * D;
            atomicAdd(&dst[tid],        c * xs[tt][tid]);
            atomicAdd(&dst[tid + 256],  c * xs[tt][tid + 256]);
        }
        if (tid < KTOP) atomicAdd(&state_ws[(size_t)b * S + gidx[tid]], spv[tid]);
        __syncthreads();
    }
}

// ---------- state finalize: signed-abs-softmax -> out[...,0] ----------
__global__ void k_state_final(const float* __restrict__ state_ws,
                              float* __restrict__ out) {
    int b = blockIdx.x;
    int tid = threadIdx.x;
    __shared__ float red[256];
    const float* sp = state_ws + (size_t)b * S;
    float m = -1e30f;
    for (int s = tid; s < S; s += 256) m = fmaxf(m, fabsf(sp[s]));
    red[tid] = m; __syncthreads();
    for (int off = 128; off > 0; off >>= 1) {
        if (tid < off) red[tid] = fmaxf(red[tid], red[tid + off]);
        __syncthreads();
    }
    m = red[0]; __syncthreads();
    float sum = 0.f;
    for (int s = tid; s < S; s += 256) sum += expf(fabsf(sp[s]) - m);
    red[tid] = sum; __syncthreads();
    for (int off = 128; off > 0; off >>= 1) {
        if (tid < off) red[tid] += red[tid + off];
        __syncthreads();
    }
    float inv = 1.0f / red[0];
    for (int s = tid; s < S; s += 256) {
        float v = sp[s];
        out[((size_t)b * S + s) * (D + 1)] = signf(v) * expf(fabsf(v) - m) * inv;
    }
}

// ---------- val row normalize (in place) ----------
__global__ void k_val_norm(float* __restrict__ val1) {
    int wave = threadIdx.x >> 6;
    int lane = threadIdx.x & 63;
    int row = blockIdx.x * 4 + wave;
    float* p = val1 + (size_t)row * D;
    float vals[8];
    float ss = 0.f;
#pragma unroll
    for (int i = 0; i < 8; i++) {
        float v = p[lane + 64 * i];
        vals[i] = v;
        ss += v * v;
    }
#pragma unroll
    for (int off = 32; off > 0; off >>= 1) ss += __shfl_xor(ss, off, 64);
    float scale = 1.0f / (sqrtf(ss) + 1e-6f);
#pragma unroll
    for (int i = 0; i < 8; i++) p[lane + 64 * i] = vals[i] * scale;
}

// ---------- q / kT projections ----------
__global__ void __launch_bounds__(256) k_qk(const float* __restrict__ val1,
                                            const float* __restrict__ pair_a,
                                            const float* __restrict__ pair_b,
                                            float* __restrict__ q,
                                            float* __restrict__ kkT) {
    __shared__ float vrow[NR][D];   // 32 KB
    __shared__ float redq[256];
    __shared__ float redk[256];
    int tid = threadIdx.x;
    int rowbase = blockIdx.x * NR;    // = b*S + sbase (never straddles b)
    int b = rowbase / S;
    int sbase = rowbase & (S - 1);
    for (int rr = 0; rr < NR; rr++) {
        const float* p = val1 + (size_t)(rowbase + rr) * D;
        for (int d = tid; d < D; d += 256) vrow[rr][d] = p[d];
    }
    __syncthreads();
    int r = tid & 63, grp = tid >> 6;
    float accq[NR], acck[NR];
#pragma unroll
    for (int rr = 0; rr < NR; rr++) { accq[rr] = 0.f; acck[rr] = 0.f; }
    for (int d = grp * 128; d < grp * 128 + 128; d++) {
        float a  = pair_a[(size_t)d * R + r];
        float bb = pair_b[(size_t)d * R + r];
#pragma unroll
        for (int rr = 0; rr < NR; rr++) {
            float v = vrow[rr][d];
            accq[rr] += v * a;
            acck[rr] += v * bb;
        }
    }
    for (int rr = 0; rr < NR; rr++) {
        redq[tid] = accq[rr]; redk[tid] = acck[rr];
        __syncthreads();
        if (tid < 64) {
            float qv = redq[tid] + redq[tid + 64] + redq[tid + 128] + redq[tid + 192];
            float kv = redk[tid] + redk[tid + 64] + redk[tid + 128] + redk[tid + 192];
            q[(size_t)(rowbase + rr) * R + tid] = qv;
            kkT[((size_t)b * R + tid) * S + (sbase + rr)] = kv;
        }
        __syncthreads();
    }
}

// ---------- propagation: p = q.kT, topk edges, residual mix, norm, out ----------
__global__ void __launch_bounds__(256) k_prop(const float* __restrict__ q,
                                              const float* __restrict__ kkT,
                                              const float* __restrict__ val1,
                                              float* __restrict__ out) {
    __shared__ float prow[NI][S];   // 32 KB
    __shared__ float qrow[NI][R];
    __shared__ float red[256];
    __shared__ int   redi[256];
    __shared__ float gval[KTOP];
    __shared__ int   gidx[KTOP];
    __shared__ float ew[KTOP];

    int tid = threadIdx.x;
    int ibase = blockIdx.x * NI;     // global row = b*S + i (never straddles b)
    int b = ibase / S;

    for (int rr = 0; rr < NI; rr++)
        for (int r = tid; r < R; r += 256)
            qrow[rr][r] = q[(size_t)(ibase + rr) * R + r];
    __syncthreads();

    // p rows
    for (int i = 0; i < S / 256; i++) {
        int j = tid + 256 * i;
        float acc[NI] = {0.f, 0.f, 0.f, 0.f};
        for (int r = 0; r < R; r++) {
            float kv = kkT[((size_t)b * R + r) * S + j];
#pragma unroll
            for (int rr = 0; rr < NI; rr++) acc[rr] += qrow[rr][r] * kv;
        }
        for (int rr = 0; rr < NI; rr++) prow[rr][j] = acc[rr];
    }
    __syncthreads();

    int lane = tid & 63, wv = tid >> 6;
    for (int rr = 0; rr < NI; rr++) {
        // top-16 edges by |p|
        for (int k = 0; k < KTOP; k++) {
            float bestv = -1.f; int besti = 0;
            for (int i = 0; i < S / 256; i++) {
                int j = tid + 256 * i;
                float a = fabsf(prow[rr][j]);
                if (a > bestv) { bestv = a; besti = j; }
            }
#pragma unroll
            for (int off = 32; off > 0; off >>= 1) {
                float ov = __shfl_xor(bestv, off, 64);
                int   oi = __shfl_xor(besti, off, 64);
                if (ov > bestv || (ov == bestv && oi < besti)) { bestv = ov; besti = oi; }
            }
            if (lane == 0) { red[wv] = bestv; redi[wv] = besti; }
            __syncthreads();
            if (tid == 0) {
                float bv = red[0]; int bi = redi[0];
                for (int w2 = 1; w2 < 4; w2++) {
                    if (red[w2] > bv || (red[w2] == bv && redi[w2] < bi)) {
                        bv = red[w2]; bi = redi[w2];
                    }
                }
                gval[k] = prow[rr][bi]; gidx[k] = bi;
                prow[rr][bi] = 0.0f;
            }
            __syncthreads();
        }
        // signed-abs-softmax edge weights
        if (tid == 0) {
            float m = fabsf(gval[0]);
            float e[KTOP];
            float sum = 0.f;
            for (int k = 0; k < KTOP; k++) { e[k] = expf(fabsf(gval[k]) - m); sum += e[k]; }
            float inv = 1.0f / sum;
            for (int k = 0; k < KTOP; k++) ew[k] = signf(gval[k]) * e[k] * inv;
        }
        __syncthreads();
        // gather neighbors, residual add, unit-norm, write out[...,1:]
        {
            const float* self = val1 + (size_t)(ibase + rr) * D;
            float a0 = self[tid], a1 = self[tid + 256];
            for (int k = 0; k < KTOP; k++) {
                const float* nb = val1 + ((size_t)b * S + gidx[k]) * D;
                float w = ew[k];
                a0 += w * nb[tid];
                a1 += w * nb[tid + 256];
            }
            red[tid] = a0 * a0 + a1 * a1; __syncthreads();
            for (int off = 128; off > 0; off >>= 1) {
                if (tid < off) red[tid] += red[tid + off];
                __syncthreads();
            }
            float scale = 1.0f / (sqrtf(red[0]) + 1e-6f);
            float* op = out + (size_t)(ibase + rr) * (D + 1) + 1;
            op[tid] = a0 * scale;
            op[tid + 256] = a1 * scale;
        }
        __syncthreads();
    }
}

extern "C" void kernel_launch(void* const* d_in, const int* in_sizes, int n_in,
                              void* d_out, int out_size, void* d_ws, size_t ws_size,
                              hipStream_t stream) {
    (void)in_sizes; (void)n_in; (void)out_size; (void)ws_size;
    const float* x          = (const float*)d_in[0];
    const float* init_state = (const float*)d_in[1];
    const float* init_val   = (const float*)d_in[2];
    const float* route_a    = (const float*)d_in[3];
    const float* route_b    = (const float*)d_in[4];
    const float* pair_a     = (const float*)d_in[5];
    const float* pair_b     = (const float*)d_in[6];
    float* out = (float*)d_out;

    float* ws       = (float*)d_ws;
    float* val1     = ws;                           // B*S*D
    float* q        = val1 + (size_t)B * S * D;     // B*S*R
    float* kkT      = q    + (size_t)B * S * R;     // B*R*S (transposed)
    float* state_ws = kkT  + (size_t)B * R * S;     // B*S

    hipLaunchKernelGGL(k_init_state, dim3(B), dim3(256), 0, stream, init_state, state_ws);
    hipLaunchKernelGGL(k_init_val, dim3(B * S / 4), dim3(256), 0, stream, init_val, val1);
    hipLaunchKernelGGL(k_write, dim3(B * T / NT), dim3(256), 0, stream,
                       x, route_a, route_b, val1, state_ws);
    hipLaunchKernelGGL(k_state_final, dim3(B), dim3(256), 0, stream, state_ws, out);
    hipLaunchKernelGGL(k_val_norm, dim3(B * S / 4), dim3(256), 0, stream, val1);
    hipLaunchKernelGGL(k_qk, dim3(B * S / NR), dim3(256), 0, stream,
                       val1, pair_a, pair_b, q, kkT);
    hipLaunchKernelGGL(k_prop, dim3(B * S / NI), dim3(256), 0, stream,
                       q, kkT, val1, out);
}

// Round 2
// 2650.870 us; speedup vs baseline: 1.6759x; 1.6759x over previous
//
#include <hip/hip_runtime.h>
#include <cmath>

namespace {
constexpr int B = 8;
constexpr int T = 2048;
constexpr int D = 512;
constexpr int S = 2048;
constexpr int R = 64;
constexpr int KTOP = 16;
constexpr int NT = 4;    // tokens per block in score kernel
constexpr int NR = 16;   // rows per block in qk kernel
constexpr int NI = 4;    // rows per block in prop kernel
constexpr int CAP = 256; // bin capacity per (b,slot); overflow -> atomic fallback

__device__ __forceinline__ float signf(float v) {
    return (v > 0.f) ? 1.f : ((v < 0.f) ? -1.f : 0.f);
}
} // namespace

// ---------- state init: state_ws[b][s] = sign * softmax(|init_state|) ----------
__global__ void k_init_state(const float* __restrict__ init_state,
                             float* __restrict__ state_ws) {
    int b = blockIdx.x;
    int tid = threadIdx.x;
    __shared__ float red[256];
    float m = -1e30f;
    for (int s = tid; s < S; s += 256) m = fmaxf(m, fabsf(init_state[s]));
    red[tid] = m; __syncthreads();
    for (int off = 128; off > 0; off >>= 1) {
        if (tid < off) red[tid] = fmaxf(red[tid], red[tid + off]);
        __syncthreads();
    }
    m = red[0]; __syncthreads();
    float sum = 0.f;
    for (int s = tid; s < S; s += 256) sum += expf(fabsf(init_state[s]) - m);
    red[tid] = sum; __syncthreads();
    for (int off = 128; off > 0; off >>= 1) {
        if (tid < off) red[tid] += red[tid + off];
        __syncthreads();
    }
    float inv = 1.0f / red[0];
    for (int s = tid; s < S; s += 256) {
        float v = init_state[s];
        state_ws[(size_t)b * S + s] = signf(v) * expf(fabsf(v) - m) * inv;
    }
}

// ---------- val broadcast init: val1[b][s][:] = unit_norm(init_val[s]) ----------
__global__ void k_bcast(const float* __restrict__ init_val,
                        float* __restrict__ val1) {
    int wave = threadIdx.x >> 6;
    int lane = threadIdx.x & 63;
    int row = blockIdx.x * 4 + wave;        // row = b*S + s
    int s = row & (S - 1);
    const float* src = init_val + (size_t)s * D;
    float vals[8];
    float ss = 0.f;
#pragma unroll
    for (int i = 0; i < 8; i++) {
        float v = src[lane + 64 * i];
        vals[i] = v;
        ss += v * v;
    }
#pragma unroll
    for (int off = 32; off > 0; off >>= 1) ss += __shfl_xor(ss, off, 64);
    float scale = 1.0f / (sqrtf(ss) + 1e-6f);
    float* dst = val1 + (size_t)row * D;
#pragma unroll
    for (int i = 0; i < 8; i++) dst[lane + 64 * i] = vals[i] * scale;
}

// ---------- score stage: route scores -> per-wave topk -> bin lists ----------
__global__ void __launch_bounds__(256) k_score(const float* __restrict__ x,
                                               const float* __restrict__ route_a,
                                               const float* __restrict__ route_b,
                                               float* __restrict__ val1,
                                               float* __restrict__ state_ws,
                                               float* __restrict__ coef,
                                               int* __restrict__ bincount,
                                               int* __restrict__ binlist) {
    __shared__ float xs[NT][D];     // 8 KB
    __shared__ float sc[NT][S];     // 32 KB
    __shared__ float xr[NT][R];     // 1 KB
    __shared__ float red[256];

    int tid = threadIdx.x;
    int lane = tid & 63, wv = tid >> 6;
    int tb = blockIdx.x * NT;       // global token base (block never straddles b)
    int b = tb / T;
    int t0 = tb % T;                // token base within batch

    // load 4 x rows (vectorized)
    {
        const float4* xg = (const float4*)(x + (size_t)tb * D);
        float4* xls = (float4*)&xs[0][0];
        xls[tid] = xg[tid];
        xls[tid + 256] = xg[tid + 256];
    }
    __syncthreads();

    // xr = x . route_a
    {
        int r = lane, grp = wv;
        float acc[NT] = {0.f, 0.f, 0.f, 0.f};
        for (int d = grp * 128; d < grp * 128 + 128; d++) {
            float a = route_a[(size_t)d * R + r];
#pragma unroll
            for (int tt = 0; tt < NT; tt++) acc[tt] += xs[tt][d] * a;
        }
        for (int tt = 0; tt < NT; tt++) {
            red[tid] = acc[tt]; __syncthreads();
            if (tid < 64)
                xr[tt][tid] = red[tid] + red[tid + 64] + red[tid + 128] + red[tid + 192];
            __syncthreads();
        }
    }

    // scores = xr . route_b (block cooperative; route_b tile reused by 4 tokens)
    for (int i = 0; i < S / 256; i++) {
        int s = tid + 256 * i;
        float acc[NT] = {0.f, 0.f, 0.f, 0.f};
        for (int r = 0; r < R; r++) {
            float bv = route_b[(size_t)r * S + s];
#pragma unroll
            for (int tt = 0; tt < NT; tt++) acc[tt] += xr[tt][r] * bv;
        }
        for (int tt = 0; tt < NT; tt++) sc[tt][s] = acc[tt];
    }
    __syncthreads();

    // ---- per-wave from here: wave wv owns token tt = wv ----
    int tt = wv;
    int tloc = t0 + tt;             // token within batch
    int tglob = tb + tt;            // global token

    // x inverse norm (per wave)
    float ss = 0.f;
#pragma unroll
    for (int i = 0; i < 8; i++) { float v = xs[tt][lane + 64 * i]; ss += v * v; }
#pragma unroll
    for (int off = 32; off > 0; off >>= 1) ss += __shfl_xor(ss, off, 64);
    float xinv = 1.0f / (sqrtf(ss) + 1e-6f);

    // pull scores into registers: lane covers j = lane + 64*i
    float acc[32];
#pragma unroll
    for (int i = 0; i < 32; i++) acc[i] = sc[tt][lane + 64 * i];

    // 16 rounds of wave argmax over |acc|, winner zeroed; lane k keeps winner k
    float myg = 0.f; int myj = 0;
    for (int k = 0; k < KTOP; k++) {
        float bv = -1.f, bs = 0.f; int bj = 0;
#pragma unroll
        for (int i = 0; i < 32; i++) {
            float v = acc[i], a = fabsf(v);
            if (a > bv) { bv = a; bs = v; bj = lane + 64 * i; }
        }
#pragma unroll
        for (int off = 32; off > 0; off >>= 1) {
            float ov = __shfl_xor(bv, off, 64);
            float os = __shfl_xor(bs, off, 64);
            int   oj = __shfl_xor(bj, off, 64);
            if (ov > bv || (ov == bv && oj < bj)) { bv = ov; bs = os; bj = oj; }
        }
        if (lane == k) { myg = bs; myj = bj; }
#pragma unroll
        for (int i = 0; i < 32; i++) if (bj == lane + 64 * i) acc[i] = 0.f;
    }

    // signed-abs-softmax over the 16 winners (lane k holds winner k)
    float m = __shfl(fabsf(myg), 0);                // round 0 winner = abs max
    float e = (lane < KTOP) ? expf(fabsf(myg) - m) : 0.f;
    float esum = e;
#pragma unroll
    for (int off = 8; off > 0; off >>= 1) esum += __shfl_xor(esum, off, 64);
    esum = __shfl(esum, 0);                         // sum over lanes 0..15
    float w = signf(myg) * e / esum;
    float coefv = w * xinv;

    unsigned long long ovf = 0ull;
    int pos = 0;
    if (lane < KTOP) {
        float sp = (myg > 20.f) ? myg : log1pf(expf(myg));
        atomicAdd(&state_ws[(size_t)b * S + myj], sp);
        pos = atomicAdd(&bincount[(size_t)b * S + myj], 1);
        if (pos < CAP) {
            binlist[((size_t)b * S + myj) * CAP + pos] = (tloc << 4) | lane;
            coef[(size_t)tglob * KTOP + lane] = coefv;
        }
    }
    ovf = __ballot(lane < KTOP && pos >= CAP);
    // overflow fallback (essentially never): wave-cooperative atomics
    while (ovf) {
        int src = __ffsll(ovf) - 1;
        int j = __shfl(myj, src);
        float c = __shfl(coefv, src);
        float* dst = val1 + ((size_t)b * S + j) * D;
#pragma unroll
        for (int i = 0; i < 8; i++)
            atomicAdd(&dst[lane + 64 * i], c * xs[tt][lane + 64 * i]);
        ovf &= ovf - 1;
    }
}

// ---------- accumulate bins: val1[row] = unit_norm(val1[row] + sum c*x) ----------
__global__ void __launch_bounds__(256) k_accum(const float* __restrict__ x,
                                               const float* __restrict__ coef,
                                               const int* __restrict__ bincount,
                                               const int* __restrict__ binlist,
                                               float* __restrict__ val1) {
    int lane = threadIdx.x & 63, wv = threadIdx.x >> 6;
    int row = blockIdx.x * 4 + wv;      // row = b*S + s
    int b = row >> 11;                  // S = 2048
    float* vp = val1 + (size_t)row * D;
    float a[8];
#pragma unroll
    for (int i = 0; i < 8; i++) a[i] = vp[lane + 64 * i];
    int n = bincount[row]; if (n > CAP) n = CAP;
    const int* lp = binlist + (size_t)row * CAP;
    for (int e = 0; e < n; e++) {
        int ent = lp[e];
        int tl = ent >> 4, k = ent & 15;
        float c = coef[((size_t)b * T + tl) * KTOP + k];
        const float* xp = x + ((size_t)b * T + tl) * D;
#pragma unroll
        for (int i = 0; i < 8; i++) a[i] += c * xp[lane + 64 * i];
    }
    float ss = 0.f;
#pragma unroll
    for (int i = 0; i < 8; i++) ss += a[i] * a[i];
#pragma unroll
    for (int off = 32; off > 0; off >>= 1) ss += __shfl_xor(ss, off, 64);
    float scale = 1.0f / (sqrtf(ss) + 1e-6f);
#pragma unroll
    for (int i = 0; i < 8; i++) vp[lane + 64 * i] = a[i] * scale;
}

// ---------- state finalize: signed-abs-softmax -> out[...,0] ----------
__global__ void k_state_final(const float* __restrict__ state_ws,
                              float* __restrict__ out) {
    int b = blockIdx.x;
    int tid = threadIdx.x;
    __shared__ float red[256];
    const float* sp = state_ws + (size_t)b * S;
    float m = -1e30f;
    for (int s = tid; s < S; s += 256) m = fmaxf(m, fabsf(sp[s]));
    red[tid] = m; __syncthreads();
    for (int off = 128; off > 0; off >>= 1) {
        if (tid < off) red[tid] = fmaxf(red[tid], red[tid + off]);
        __syncthreads();
    }
    m = red[0]; __syncthreads();
    float sum = 0.f;
    for (int s = tid; s < S; s += 256) sum += expf(fabsf(sp[s]) - m);
    red[tid] = sum; __syncthreads();
    for (int off = 128; off > 0; off >>= 1) {
        if (tid < off) red[tid] += red[tid + off];
        __syncthreads();
    }
    float inv = 1.0f / red[0];
    for (int s = tid; s < S; s += 256) {
        float v = sp[s];
        out[((size_t)b * S + s) * (D + 1)] = signf(v) * expf(fabsf(v) - m) * inv;
    }
}

// ---------- q / kT projections ----------
__global__ void __launch_bounds__(256) k_qk(const float* __restrict__ val1,
                                            const float* __restrict__ pair_a,
                                            const float* __restrict__ pair_b,
                                            float* __restrict__ q,
                                            float* __restrict__ kkT) {
    __shared__ float vrow[NR][D];   // 32 KB
    __shared__ float redq[256];
    __shared__ float redk[256];
    int tid = threadIdx.x;
    int rowbase = blockIdx.x * NR;    // = b*S + sbase (never straddles b)
    int b = rowbase / S;
    int sbase = rowbase & (S - 1);
    for (int rr = 0; rr < NR; rr++) {
        const float* p = val1 + (size_t)(rowbase + rr) * D;
        for (int d = tid; d < D; d += 256) vrow[rr][d] = p[d];
    }
    __syncthreads();
    int r = tid & 63, grp = tid >> 6;
    float accq[NR], acck[NR];
#pragma unroll
    for (int rr = 0; rr < NR; rr++) { accq[rr] = 0.f; acck[rr] = 0.f; }
    for (int d = grp * 128; d < grp * 128 + 128; d++) {
        float a  = pair_a[(size_t)d * R + r];
        float bb = pair_b[(size_t)d * R + r];
#pragma unroll
        for (int rr = 0; rr < NR; rr++) {
            float v = vrow[rr][d];
            accq[rr] += v * a;
            acck[rr] += v * bb;
        }
    }
    for (int rr = 0; rr < NR; rr++) {
        redq[tid] = accq[rr]; redk[tid] = acck[rr];
        __syncthreads();
        if (tid < 64) {
            float qv = redq[tid] + redq[tid + 64] + redq[tid + 128] + redq[tid + 192];
            float kv = redk[tid] + redk[tid + 64] + redk[tid + 128] + redk[tid + 192];
            q[(size_t)(rowbase + rr) * R + tid] = qv;
            kkT[((size_t)b * R + tid) * S + (sbase + rr)] = kv;
        }
        __syncthreads();
    }
}

// ---------- propagation: p = q.kT, per-wave topk, gather mix, norm, out ----------
__global__ void __launch_bounds__(256) k_prop(const float* __restrict__ q,
                                              const float* __restrict__ kkT,
                                              const float* __restrict__ val1,
                                              float* __restrict__ out) {
    __shared__ float prow[NI][S];   // 32 KB
    __shared__ float qrow[NI][R];

    int tid = threadIdx.x;
    int lane = tid & 63, wv = tid >> 6;
    int ibase = blockIdx.x * NI;     // global row base (never straddles b)
    int b = ibase >> 11;             // S = 2048

    if (tid < NI * R) {
        int rr = tid >> 6, r = tid & 63;
        qrow[rr][r] = q[(size_t)(ibase + rr) * R + r];
    }
    __syncthreads();

    // p rows (block cooperative; kkT tile reused by 4 rows)
    for (int i = 0; i < S / 256; i++) {
        int j = tid + 256 * i;
        float acc[NI] = {0.f, 0.f, 0.f, 0.f};
        for (int r = 0; r < R; r++) {
            float kv = kkT[((size_t)b * R + r) * S + j];
#pragma unroll
            for (int rr = 0; rr < NI; rr++) acc[rr] += qrow[rr][r] * kv;
        }
        for (int rr = 0; rr < NI; rr++) prow[rr][j] = acc[rr];
    }
    __syncthreads();

    // ---- per-wave: wave wv owns row ibase + wv ----
    int row = ibase + wv;

    float acc[32];
#pragma unroll
    for (int i = 0; i < 32; i++) acc[i] = prow[wv][lane + 64 * i];

    float myg = 0.f; int myj = 0;
    for (int k = 0; k < KTOP; k++) {
        float bv = -1.f, bs = 0.f; int bj = 0;
#pragma unroll
        for (int i = 0; i < 32; i++) {
            float v = acc[i], a = fabsf(v);
            if (a > bv) { bv = a; bs = v; bj = lane + 64 * i; }
        }
#pragma unroll
        for (int off = 32; off > 0; off >>= 1) {
            float ov = __shfl_xor(bv, off, 64);
            float os = __shfl_xor(bs, off, 64);
            int   oj = __shfl_xor(bj, off, 64);
            if (ov > bv || (ov == bv && oj < bj)) { bv = ov; bs = os; bj = oj; }
        }
        if (lane == k) { myg = bs; myj = bj; }
#pragma unroll
        for (int i = 0; i < 32; i++) if (bj == lane + 64 * i) acc[i] = 0.f;
    }

    float m = __shfl(fabsf(myg), 0);
    float e = (lane < KTOP) ? expf(fabsf(myg) - m) : 0.f;
    float esum = e;
#pragma unroll
    for (int off = 8; off > 0; off >>= 1) esum += __shfl_xor(esum, off, 64);
    esum = __shfl(esum, 0);
    float myw = signf(myg) * e / esum;

    // gather neighbors, residual add, unit-norm, write out[...,1:]
    const float* self = val1 + (size_t)row * D;
    float a[8];
#pragma unroll
    for (int i = 0; i < 8; i++) a[i] = self[lane + 64 * i];
    for (int k = 0; k < KTOP; k++) {
        int j = __shfl(myj, k);
        float w = __shfl(myw, k);
        const float* nb = val1 + ((size_t)b * S + j) * D;
#pragma unroll
        for (int i = 0; i < 8; i++) a[i] += w * nb[lane + 64 * i];
    }
    float ss = 0.f;
#pragma unroll
    for (int i = 0; i < 8; i++) ss += a[i] * a[i];
#pragma unroll
    for (int off = 32; off > 0; off >>= 1) ss += __shfl_xor(ss, off, 64);
    float scale = 1.0f / (sqrtf(ss) + 1e-6f);
    float* op = out + (size_t)row * (D + 1) + 1;
#pragma unroll
    for (int i = 0; i < 8; i++) op[lane + 64 * i] = a[i] * scale;
}

extern "C" void kernel_launch(void* const* d_in, const int* in_sizes, int n_in,
                              void* d_out, int out_size, void* d_ws, size_t ws_size,
                              hipStream_t stream) {
    (void)in_sizes; (void)n_in; (void)out_size; (void)ws_size;
    const float* x          = (const float*)d_in[0];
    const float* init_state = (const float*)d_in[1];
    const float* init_val   = (const float*)d_in[2];
    const float* route_a    = (const float*)d_in[3];
    const float* route_b    = (const float*)d_in[4];
    const float* pair_a     = (const float*)d_in[5];
    const float* pair_b     = (const float*)d_in[6];
    float* out = (float*)d_out;

    float* ws       = (float*)d_ws;
    float* val1     = ws;                             // B*S*D
    float* q        = val1 + (size_t)B * S * D;       // B*S*R
    float* kkT      = q    + (size_t)B * S * R;       // B*R*S
    float* state_ws = kkT  + (size_t)B * R * S;       // B*S
    float* coef     = state_ws + (size_t)B * S;       // B*T*K
    int*   bincount = (int*)(coef + (size_t)B * T * KTOP);   // B*S
    int*   binlist  = bincount + (size_t)B * S;              // B*S*CAP

    hipMemsetAsync(bincount, 0, (size_t)B * S * sizeof(int), stream);
    hipLaunchKernelGGL(k_init_state, dim3(B), dim3(256), 0, stream, init_state, state_ws);
    hipLaunchKernelGGL(k_bcast, dim3(B * S / 4), dim3(256), 0, stream, init_val, val1);
    hipLaunchKernelGGL(k_score, dim3(B * T / NT), dim3(256), 0, stream,
                       x, route_a, route_b, val1, state_ws, coef, bincount, binlist);
    hipLaunchKernelGGL(k_state_final, dim3(B), dim3(256), 0, stream, state_ws, out);
    hipLaunchKernelGGL(k_accum, dim3(B * S / 4), dim3(256), 0, stream,
                       x, coef, bincount, binlist, val1);
    hipLaunchKernelGGL(k_qk, dim3(B * S / NR), dim3(256), 0, stream,
                       val1, pair_a, pair_b, q, kkT);
    hipLaunchKernelGGL(k_prop, dim3(B * S / NI), dim3(256), 0, stream,
                       q, kkT, val1, out);
}

// Round 3
// 646.148 us; speedup vs baseline: 6.8753x; 4.1026x over previous
//
#include <hip/hip_runtime.h>
#include <cmath>

namespace {
constexpr int B = 8;
constexpr int T = 2048;
constexpr int D = 512;
constexpr int S = 2048;
constexpr int R = 64;
constexpr int KTOP = 16;
constexpr int NT = 4;    // tokens per block in score kernel
constexpr int NR = 16;   // rows per block in qk kernel
constexpr int NI = 4;    // rows per block in pscore kernel
constexpr int CAP = 256; // bin capacity per (b,slot); overflow -> atomic fallback

__device__ __forceinline__ float signf(float v) {
    return (v > 0.f) ? 1.f : ((v < 0.f) ? -1.f : 0.f);
}
} // namespace

// ---------- state init: state_ws[b][s] = sign * softmax(|init_state|) ----------
__global__ void k_init_state(const float* __restrict__ init_state,
                             float* __restrict__ state_ws) {
    int b = blockIdx.x;
    int tid = threadIdx.x;
    __shared__ float red[256];
    float m = -1e30f;
    for (int s = tid; s < S; s += 256) m = fmaxf(m, fabsf(init_state[s]));
    red[tid] = m; __syncthreads();
    for (int off = 128; off > 0; off >>= 1) {
        if (tid < off) red[tid] = fmaxf(red[tid], red[tid + off]);
        __syncthreads();
    }
    m = red[0]; __syncthreads();
    float sum = 0.f;
    for (int s = tid; s < S; s += 256) sum += expf(fabsf(init_state[s]) - m);
    red[tid] = sum; __syncthreads();
    for (int off = 128; off > 0; off >>= 1) {
        if (tid < off) red[tid] += red[tid + off];
        __syncthreads();
    }
    float inv = 1.0f / red[0];
    for (int s = tid; s < S; s += 256) {
        float v = init_state[s];
        state_ws[(size_t)b * S + s] = signf(v) * expf(fabsf(v) - m) * inv;
    }
}

// ---------- val broadcast init: val1[b][s][:] = unit_norm(init_val[s]) ----------
__global__ void k_bcast(const float* __restrict__ init_val,
                        float* __restrict__ val1) {
    int wv = threadIdx.x >> 6;
    int lane = threadIdx.x & 63;
    int row = blockIdx.x * 4 + wv;        // row = b*S + s
    int s = row & (S - 1);
    const float4* src = (const float4*)(init_val + (size_t)s * D);
    float4 v0 = src[lane], v1 = src[lane + 64];
    float ss = v0.x * v0.x + v0.y * v0.y + v0.z * v0.z + v0.w * v0.w
             + v1.x * v1.x + v1.y * v1.y + v1.z * v1.z + v1.w * v1.w;
#pragma unroll
    for (int off = 32; off > 0; off >>= 1) ss += __shfl_xor(ss, off, 64);
    float sc = 1.0f / (sqrtf(ss) + 1e-6f);
    v0.x *= sc; v0.y *= sc; v0.z *= sc; v0.w *= sc;
    v1.x *= sc; v1.y *= sc; v1.z *= sc; v1.w *= sc;
    float4* dst = (float4*)(val1 + (size_t)row * D);
    dst[lane] = v0; dst[lane + 64] = v1;
}

// ---------- score stage: route scores -> per-wave LDS topk -> bin lists ----------
__global__ void __launch_bounds__(256) k_score(const float* __restrict__ x,
                                               const float* __restrict__ route_a,
                                               const float* __restrict__ route_b,
                                               float* __restrict__ val1,
                                               float* __restrict__ state_ws,
                                               float* __restrict__ coef,
                                               int* __restrict__ bincount,
                                               int* __restrict__ binlist) {
    __shared__ __align__(16) float xs[NT][D];     // 8 KB
    __shared__ __align__(16) float sc[NT][S];     // 32 KB
    __shared__ __align__(16) float xr[NT][R];     // 1 KB
    __shared__ float red[256];

    int tid = threadIdx.x;
    int lane = tid & 63, wv = tid >> 6;
    int tb = blockIdx.x * NT;       // global token base (block never straddles b)
    int b = tb >> 11;               // T = 2048
    int t0 = tb & (T - 1);

    // load 4 x rows (vectorized)
    {
        const float4* xg = (const float4*)(x + (size_t)tb * D);
        float4* xls = (float4*)&xs[0][0];
        xls[tid] = xg[tid];
        xls[tid + 256] = xg[tid + 256];
    }
    __syncthreads();

    // xr = x . route_a
    {
        int r = lane, grp = wv;
        float acc[NT] = {0.f, 0.f, 0.f, 0.f};
        for (int d = grp * 128; d < grp * 128 + 128; d++) {
            float a = route_a[(size_t)d * R + r];
#pragma unroll
            for (int tt = 0; tt < NT; tt++) acc[tt] += xs[tt][d] * a;
        }
        for (int tt = 0; tt < NT; tt++) {
            red[tid] = acc[tt]; __syncthreads();
            if (tid < 64)
                xr[tt][tid] = red[tid] + red[tid + 64] + red[tid + 128] + red[tid + 192];
            __syncthreads();
        }
    }

    // scores = xr . route_b  (float4 over s)
    {
        const float4* rb4 = (const float4*)route_b;
#pragma unroll
        for (int i = 0; i < 2; i++) {
            int j4 = tid + 256 * i;
            float4 acc[NT];
#pragma unroll
            for (int tt = 0; tt < NT; tt++) acc[tt] = make_float4(0.f, 0.f, 0.f, 0.f);
            for (int r0 = 0; r0 < R; r0 += 4) {
                float4 xv[NT];
#pragma unroll
                for (int tt = 0; tt < NT; tt++) xv[tt] = *(const float4*)&xr[tt][r0];
#define SCORE_STEP(dr, comp)                                                   \
                {                                                              \
                    float4 bv = rb4[(size_t)(r0 + dr) * (S / 4) + j4];         \
                    _Pragma("unroll")                                          \
                    for (int tt = 0; tt < NT; tt++) {                          \
                        float c = xv[tt].comp;                                 \
                        acc[tt].x += c * bv.x; acc[tt].y += c * bv.y;          \
                        acc[tt].z += c * bv.z; acc[tt].w += c * bv.w;          \
                    }                                                          \
                }
                SCORE_STEP(0, x) SCORE_STEP(1, y) SCORE_STEP(2, z) SCORE_STEP(3, w)
#undef SCORE_STEP
            }
#pragma unroll
            for (int tt = 0; tt < NT; tt++)
                ((float4*)&sc[tt][0])[j4] = acc[tt];
        }
    }
    __syncthreads();

    // ---- per-wave from here: wave wv owns token tt = wv ----
    int tt = wv;
    int tloc = t0 + tt;
    int tglob = tb + tt;

    // x inverse norm (per wave, float4 LDS reads)
    float xinv;
    {
        const float4* xst = (const float4*)&xs[tt][0];
        float4 x0 = xst[lane], x1 = xst[lane + 64];
        float ss = x0.x * x0.x + x0.y * x0.y + x0.z * x0.z + x0.w * x0.w
                 + x1.x * x1.x + x1.y * x1.y + x1.z * x1.z + x1.w * x1.w;
#pragma unroll
        for (int off = 32; off > 0; off >>= 1) ss += __shfl_xor(ss, off, 64);
        xinv = 1.0f / (sqrtf(ss) + 1e-6f);
    }

    // 16 rounds of wave argmax over |sc[tt]| scanned from LDS (b128 reads)
    const float4* sc4 = (const float4*)&sc[tt][0];
    float myg = 0.f; int myj = 0;
    for (int k = 0; k < KTOP; k++) {
        float bv = -1.f, bs = 0.f; int bj = 0;
#pragma unroll
        for (int i = 0; i < 8; i++) {
            float4 v = sc4[lane + 64 * i];
            int jb = 4 * (lane + 64 * i);
            { float a = fabsf(v.x); if (a > bv) { bv = a; bs = v.x; bj = jb; } }
            { float a = fabsf(v.y); if (a > bv) { bv = a; bs = v.y; bj = jb + 1; } }
            { float a = fabsf(v.z); if (a > bv) { bv = a; bs = v.z; bj = jb + 2; } }
            { float a = fabsf(v.w); if (a > bv) { bv = a; bs = v.w; bj = jb + 3; } }
        }
#pragma unroll
        for (int off = 32; off > 0; off >>= 1) {
            float ov = __shfl_xor(bv, off, 64);
            float os = __shfl_xor(bs, off, 64);
            int   oj = __shfl_xor(bj, off, 64);
            if (ov > bv || (ov == bv && oj < bj)) { bv = ov; bs = os; bj = oj; }
        }
        if (lane == k) { myg = bs; myj = bj; }
        if (lane == 0) sc[tt][bj] = 0.f;   // zero winner (same-wave LDS, ordered)
    }

    // signed-abs-softmax over the 16 winners (lane k holds winner k)
    float m = __shfl(fabsf(myg), 0);
    float e = (lane < KTOP) ? expf(fabsf(myg) - m) : 0.f;
    float esum = e;
#pragma unroll
    for (int off = 8; off > 0; off >>= 1) esum += __shfl_xor(esum, off, 64);
    esum = __shfl(esum, 0);
    float w = signf(myg) * e / esum;
    float coefv = w * xinv;

    unsigned long long ovf = 0ull;
    int pos = 0;
    if (lane < KTOP) {
        float sp = (myg > 20.f) ? myg : log1pf(expf(myg));
        atomicAdd(&state_ws[(size_t)b * S + myj], sp);
        pos = atomicAdd(&bincount[(size_t)b * S + myj], 1);
        if (pos < CAP) {
            binlist[((size_t)b * S + myj) * CAP + pos] = (tloc << 4) | lane;
            coef[(size_t)tglob * KTOP + lane] = coefv;
        }
    }
    ovf = __ballot(lane < KTOP && pos >= CAP);
    while (ovf) {   // overflow fallback (essentially never)
        int src = __ffsll(ovf) - 1;
        int j = __shfl(myj, src);
        float c = __shfl(coefv, src);
        float* dst = val1 + ((size_t)b * S + j) * D;
#pragma unroll
        for (int i = 0; i < 8; i++)
            atomicAdd(&dst[lane + 64 * i], c * xs[tt][lane + 64 * i]);
        ovf &= ovf - 1;
    }
}

// ---------- accumulate bins: val1[row] = unit_norm(val1[row] + sum c*x) ----------
__global__ void __launch_bounds__(256) k_accum(const float* __restrict__ x,
                                               const float* __restrict__ coef,
                                               const int* __restrict__ bincount,
                                               const int* __restrict__ binlist,
                                               float* __restrict__ val1) {
    int lane = threadIdx.x & 63, wv = threadIdx.x >> 6;
    int row = blockIdx.x * 4 + wv;      // row = b*S + s
    int b = row >> 11;                  // S = 2048
    float4* vp4 = (float4*)(val1 + (size_t)row * D);
    float4 a0 = vp4[lane], a1 = vp4[lane + 64];
    int n = bincount[row]; if (n > CAP) n = CAP;
    const int* lp = binlist + (size_t)row * CAP;
    for (int base = 0; base < n; base += 64) {
        int mm = n - base; if (mm > 64) mm = 64;
        int ent = 0; float cc = 0.f;
        if (lane < mm) {
            ent = lp[base + lane];
            cc = coef[((size_t)b * T + (ent >> 4)) * KTOP + (ent & 15)];
        }
        for (int k = 0; k < mm; k++) {
            int e2 = __shfl(ent, k);
            float c = __shfl(cc, k);
            const float4* xp4 = (const float4*)(x + ((size_t)b * T + (e2 >> 4)) * D);
            float4 v0 = xp4[lane], v1 = xp4[lane + 64];
            a0.x += c * v0.x; a0.y += c * v0.y; a0.z += c * v0.z; a0.w += c * v0.w;
            a1.x += c * v1.x; a1.y += c * v1.y; a1.z += c * v1.z; a1.w += c * v1.w;
        }
    }
    float ss = a0.x * a0.x + a0.y * a0.y + a0.z * a0.z + a0.w * a0.w
             + a1.x * a1.x + a1.y * a1.y + a1.z * a1.z + a1.w * a1.w;
#pragma unroll
    for (int off = 32; off > 0; off >>= 1) ss += __shfl_xor(ss, off, 64);
    float sc = 1.0f / (sqrtf(ss) + 1e-6f);
    a0.x *= sc; a0.y *= sc; a0.z *= sc; a0.w *= sc;
    a1.x *= sc; a1.y *= sc; a1.z *= sc; a1.w *= sc;
    vp4[lane] = a0; vp4[lane + 64] = a1;
}

// ---------- state finalize: signed-abs-softmax -> out[...,0] ----------
__global__ void k_state_final(const float* __restrict__ state_ws,
                              float* __restrict__ out) {
    int b = blockIdx.x;
    int tid = threadIdx.x;
    __shared__ float red[256];
    const float* sp = state_ws + (size_t)b * S;
    float m = -1e30f;
    for (int s = tid; s < S; s += 256) m = fmaxf(m, fabsf(sp[s]));
    red[tid] = m; __syncthreads();
    for (int off = 128; off > 0; off >>= 1) {
        if (tid < off) red[tid] = fmaxf(red[tid], red[tid + off]);
        __syncthreads();
    }
    m = red[0]; __syncthreads();
    float sum = 0.f;
    for (int s = tid; s < S; s += 256) sum += expf(fabsf(sp[s]) - m);
    red[tid] = sum; __syncthreads();
    for (int off = 128; off > 0; off >>= 1) {
        if (tid < off) red[tid] += red[tid + off];
        __syncthreads();
    }
    float inv = 1.0f / red[0];
    for (int s = tid; s < S; s += 256) {
        float v = sp[s];
        out[((size_t)b * S + s) * (D + 1)] = signf(v) * expf(fabsf(v) - m) * inv;
    }
}

// ---------- q / kT projections ----------
__global__ void __launch_bounds__(256) k_qk(const float* __restrict__ val1,
                                            const float* __restrict__ pair_a,
                                            const float* __restrict__ pair_b,
                                            float* __restrict__ q,
                                            float* __restrict__ kkT) {
    __shared__ __align__(16) float vrow[NR][D];   // 32 KB
    __shared__ float redq[256];
    __shared__ float redk[256];
    int tid = threadIdx.x;
    int rowbase = blockIdx.x * NR;    // = b*S + sbase (never straddles b)
    int b = rowbase >> 11;
    int sbase = rowbase & (S - 1);
    {
        const float4* gv = (const float4*)(val1 + (size_t)rowbase * D);
        float4* lv = (float4*)&vrow[0][0];
        for (int i = tid; i < NR * D / 4; i += 256) lv[i] = gv[i];
    }
    __syncthreads();
    int r = tid & 63, grp = tid >> 6;
    float accq[NR], acck[NR];
#pragma unroll
    for (int rr = 0; rr < NR; rr++) { accq[rr] = 0.f; acck[rr] = 0.f; }
    for (int d = grp * 128; d < grp * 128 + 128; d++) {
        float a  = pair_a[(size_t)d * R + r];
        float bb = pair_b[(size_t)d * R + r];
#pragma unroll
        for (int rr = 0; rr < NR; rr++) {
            float v = vrow[rr][d];
            accq[rr] += v * a;
            acck[rr] += v * bb;
        }
    }
    for (int rr = 0; rr < NR; rr++) {
        redq[tid] = accq[rr]; redk[tid] = acck[rr];
        __syncthreads();
        if (tid < 64) {
            float qv = redq[tid] + redq[tid + 64] + redq[tid + 128] + redq[tid + 192];
            float kv = redk[tid] + redk[tid + 64] + redk[tid + 128] + redk[tid + 192];
            q[(size_t)(rowbase + rr) * R + tid] = qv;
            kkT[((size_t)b * R + tid) * S + (sbase + rr)] = kv;
        }
        __syncthreads();
    }
}

// ---------- pscore: p = q.kT (float4), per-wave LDS topk -> eidx/ew ----------
__global__ void __launch_bounds__(256) k_pscore(const float* __restrict__ q,
                                                const float* __restrict__ kkT,
                                                int* __restrict__ eidx,
                                                float* __restrict__ ew_g) {
    __shared__ __align__(16) float prow[NI][S];   // 32 KB
    __shared__ __align__(16) float qrow[NI][R];

    int tid = threadIdx.x;
    int lane = tid & 63, wv = tid >> 6;
    int ibase = blockIdx.x * NI;     // global row base (never straddles b)
    int b = ibase >> 11;             // S = 2048

    {
        int rr = tid >> 6, r = tid & 63;
        qrow[rr][r] = q[(size_t)(ibase + rr) * R + r];
    }
    __syncthreads();

    // p rows (float4 over j; kkT slice reused by 4 rows)
    {
        const float4* kk4 = (const float4*)(kkT + (size_t)b * R * S);
#pragma unroll
        for (int i = 0; i < 2; i++) {
            int j4 = tid + 256 * i;
            float4 acc[NI];
#pragma unroll
            for (int rr = 0; rr < NI; rr++) acc[rr] = make_float4(0.f, 0.f, 0.f, 0.f);
            for (int r0 = 0; r0 < R; r0 += 4) {
                float4 qv[NI];
#pragma unroll
                for (int rr = 0; rr < NI; rr++) qv[rr] = *(const float4*)&qrow[rr][r0];
#define P_STEP(dr, comp)                                                       \
                {                                                              \
                    float4 kv = kk4[(size_t)(r0 + dr) * (S / 4) + j4];         \
                    _Pragma("unroll")                                          \
                    for (int rr = 0; rr < NI; rr++) {                          \
                        float c = qv[rr].comp;                                 \
                        acc[rr].x += c * kv.x; acc[rr].y += c * kv.y;          \
                        acc[rr].z += c * kv.z; acc[rr].w += c * kv.w;          \
                    }                                                          \
                }
                P_STEP(0, x) P_STEP(1, y) P_STEP(2, z) P_STEP(3, w)
#undef P_STEP
            }
#pragma unroll
            for (int rr = 0; rr < NI; rr++)
                ((float4*)&prow[rr][0])[j4] = acc[rr];
        }
    }
    __syncthreads();

    // ---- per-wave topk on row ibase + wv ----
    int row = ibase + wv;
    const float4* p4 = (const float4*)&prow[wv][0];
    float myg = 0.f; int myj = 0;
    for (int k = 0; k < KTOP; k++) {
        float bv = -1.f, bs = 0.f; int bj = 0;
#pragma unroll
        for (int i = 0; i < 8; i++) {
            float4 v = p4[lane + 64 * i];
            int jb = 4 * (lane + 64 * i);
            { float a = fabsf(v.x); if (a > bv) { bv = a; bs = v.x; bj = jb; } }
            { float a = fabsf(v.y); if (a > bv) { bv = a; bs = v.y; bj = jb + 1; } }
            { float a = fabsf(v.z); if (a > bv) { bv = a; bs = v.z; bj = jb + 2; } }
            { float a = fabsf(v.w); if (a > bv) { bv = a; bs = v.w; bj = jb + 3; } }
        }
#pragma unroll
        for (int off = 32; off > 0; off >>= 1) {
            float ov = __shfl_xor(bv, off, 64);
            float os = __shfl_xor(bs, off, 64);
            int   oj = __shfl_xor(bj, off, 64);
            if (ov > bv || (ov == bv && oj < bj)) { bv = ov; bs = os; bj = oj; }
        }
        if (lane == k) { myg = bs; myj = bj; }
        if (lane == 0) prow[wv][bj] = 0.f;
    }

    float m = __shfl(fabsf(myg), 0);
    float e = (lane < KTOP) ? expf(fabsf(myg) - m) : 0.f;
    float esum = e;
#pragma unroll
    for (int off = 8; off > 0; off >>= 1) esum += __shfl_xor(esum, off, 64);
    esum = __shfl(esum, 0);
    float myw = signf(myg) * e / esum;

    if (lane < KTOP) {
        eidx[(size_t)row * KTOP + lane] = myj;
        ew_g[(size_t)row * KTOP + lane] = myw;
    }
}

// ---------- mix: gather neighbors, residual add, unit-norm, out[...,1:] ----------
__global__ void __launch_bounds__(256) k_mix(const int* __restrict__ eidx,
                                             const float* __restrict__ ew_g,
                                             const float* __restrict__ val1,
                                             float* __restrict__ out) {
    int lane = threadIdx.x & 63, wv = threadIdx.x >> 6;
    int row = blockIdx.x * 4 + wv;
    int b = row >> 11;

    int e_i = 0; float e_w = 0.f;
    if (lane < KTOP) {
        e_i = eidx[(size_t)row * KTOP + lane];
        e_w = ew_g[(size_t)row * KTOP + lane];
    }

    const float4* self4 = (const float4*)(val1 + (size_t)row * D);
    float4 a0 = self4[lane], a1 = self4[lane + 64];
#pragma unroll
    for (int k = 0; k < KTOP; k++) {
        int j = __shfl(e_i, k);
        float w = __shfl(e_w, k);
        const float4* nb4 = (const float4*)(val1 + ((size_t)b * S + j) * D);
        float4 v0 = nb4[lane], v1 = nb4[lane + 64];
        a0.x += w * v0.x; a0.y += w * v0.y; a0.z += w * v0.z; a0.w += w * v0.w;
        a1.x += w * v1.x; a1.y += w * v1.y; a1.z += w * v1.z; a1.w += w * v1.w;
    }
    float ss = a0.x * a0.x + a0.y * a0.y + a0.z * a0.z + a0.w * a0.w
             + a1.x * a1.x + a1.y * a1.y + a1.z * a1.z + a1.w * a1.w;
#pragma unroll
    for (int off = 32; off > 0; off >>= 1) ss += __shfl_xor(ss, off, 64);
    float sc = 1.0f / (sqrtf(ss) + 1e-6f);
    float* op = out + (size_t)row * (D + 1) + 1;
    int d0 = 4 * lane;
    op[d0 + 0] = a0.x * sc; op[d0 + 1] = a0.y * sc;
    op[d0 + 2] = a0.z * sc; op[d0 + 3] = a0.w * sc;
    op[256 + d0 + 0] = a1.x * sc; op[256 + d0 + 1] = a1.y * sc;
    op[256 + d0 + 2] = a1.z * sc; op[256 + d0 + 3] = a1.w * sc;
}

extern "C" void kernel_launch(void* const* d_in, const int* in_sizes, int n_in,
                              void* d_out, int out_size, void* d_ws, size_t ws_size,
                              hipStream_t stream) {
    (void)in_sizes; (void)n_in; (void)out_size; (void)ws_size;
    const float* x          = (const float*)d_in[0];
    const float* init_state = (const float*)d_in[1];
    const float* init_val   = (const float*)d_in[2];
    const float* route_a    = (const float*)d_in[3];
    const float* route_b    = (const float*)d_in[4];
    const float* pair_a     = (const float*)d_in[5];
    const float* pair_b     = (const float*)d_in[6];
    float* out = (float*)d_out;

    float* ws       = (float*)d_ws;
    float* val1     = ws;                             // B*S*D
    float* q        = val1 + (size_t)B * S * D;       // B*S*R
    float* kkT      = q    + (size_t)B * S * R;       // B*R*S
    float* state_ws = kkT  + (size_t)B * R * S;       // B*S
    float* coef     = state_ws + (size_t)B * S;       // B*T*K
    int*   bincount = (int*)(coef + (size_t)B * T * KTOP);   // B*S
    int*   binlist  = bincount + (size_t)B * S;              // B*S*CAP
    // eidx/ew reuse binlist space (binlist dead after k_accum)
    int*   eidx     = binlist;                               // B*S*K
    float* ew       = (float*)(binlist + (size_t)B * S * KTOP);  // B*S*K

    hipMemsetAsync(bincount, 0, (size_t)B * S * sizeof(int), stream);
    hipLaunchKernelGGL(k_init_state, dim3(B), dim3(256), 0, stream, init_state, state_ws);
    hipLaunchKernelGGL(k_bcast, dim3(B * S / 4), dim3(256), 0, stream, init_val, val1);
    hipLaunchKernelGGL(k_score, dim3(B * T / NT), dim3(256), 0, stream,
                       x, route_a, route_b, val1, state_ws, coef, bincount, binlist);
    hipLaunchKernelGGL(k_state_final, dim3(B), dim3(256), 0, stream, state_ws, out);
    hipLaunchKernelGGL(k_accum, dim3(B * S / 4), dim3(256), 0, stream,
                       x, coef, bincount, binlist, val1);
    hipLaunchKernelGGL(k_qk, dim3(B * S / NR), dim3(256), 0, stream,
                       val1, pair_a, pair_b, q, kkT);
    hipLaunchKernelGGL(k_pscore, dim3(B * S / NI), dim3(256), 0, stream,
                       q, kkT, eidx, ew);
    hipLaunchKernelGGL(k_mix, dim3(B * S / 4), dim3(256), 0, stream,
                       eidx, ew, val1, out);
}

// Round 4
// 529.731 us; speedup vs baseline: 8.3863x; 1.2198x over previous
//
#include <hip/hip_runtime.h>
#include <cmath>

namespace {
constexpr int B = 8;
constexpr int T = 2048;
constexpr int D = 512;
constexpr int S = 2048;
constexpr int R = 64;
constexpr int KTOP = 16;
constexpr int NT = 4;    // tokens per block in score kernel
constexpr int NR = 16;   // rows per block in qk kernel
constexpr int NI = 4;    // rows per block in pscore kernel
constexpr int CAP = 256; // bin capacity per (b,slot); overflow -> atomic fallback

__device__ __forceinline__ float signf(float v) {
    return (v > 0.f) ? 1.f : ((v < 0.f) ? -1.f : 0.f);
}

// Exact top-16 by |value| (ties -> lower index) over a wave-private LDS row of S
// floats. Result: lane k (k<16) gets myg = signed value, myj = index, in exact
// descending (|v|, -j) order. Row contents are preserved on the fast path.
__device__ __forceinline__ void topk16_row(float* __restrict__ row,
                                           unsigned long long* __restrict__ cand,
                                           int lane, float& myg, int& myj) {
    const float4* p4 = (const float4*)row;
    // Phase 1: per-lane abs max over 32 elements
    float lmax = 0.f;
#pragma unroll
    for (int i = 0; i < 8; i++) {
        float4 v = p4[lane + 64 * i];
        lmax = fmaxf(lmax, fmaxf(fmaxf(fabsf(v.x), fabsf(v.y)),
                                 fmaxf(fabsf(v.z), fabsf(v.w))));
    }
    // Phase 2: bitonic sort (descending) of 64 lane maxes; t = 16th largest
    {
        float v = lmax;
#pragma unroll
        for (int size = 2; size <= 64; size <<= 1) {
#pragma unroll
            for (int stride = size >> 1; stride > 0; stride >>= 1) {
                float o = __shfl_xor(v, stride, 64);
                bool takeMax = ((lane & size) == 0) == ((lane & stride) == 0);
                v = takeMax ? fmaxf(v, o) : fminf(v, o);
            }
        }
        lmax = __shfl(v, 15);
    }
    float t = lmax;
    // Phase 3: count candidates with |v| >= t, prefix-sum, compact into cand[]
    int cnt = 0;
#pragma unroll
    for (int i = 0; i < 8; i++) {
        float4 v = p4[lane + 64 * i];
        cnt += (fabsf(v.x) >= t) + (fabsf(v.y) >= t) +
               (fabsf(v.z) >= t) + (fabsf(v.w) >= t);
    }
    int off = cnt;
#pragma unroll
    for (int d = 1; d < 64; d <<= 1) {
        int o = __shfl_up(off, d, 64);
        if (lane >= d) off += o;
    }
    int total = __shfl(off, 63);
    int base = off - cnt;

    if (total <= 64) {
        int pos = base;
#pragma unroll
        for (int i = 0; i < 8; i++) {
            float4 v = p4[lane + 64 * i];
            int jb = 4 * (lane + 64 * i);
            float c[4] = {v.x, v.y, v.z, v.w};
#pragma unroll
            for (int cc = 0; cc < 4; cc++) {
                if (fabsf(c[cc]) >= t) {
                    unsigned ab = __float_as_uint(c[cc]) & 0x7fffffffu;
                    cand[pos++] = ((unsigned long long)ab << 11) |
                                  (unsigned)(2047 - (jb + cc));
                }
            }
        }
        // Phase 4: bitonic sort (descending) of up to 64 u64 keys
        unsigned long long key = (lane < total) ? cand[lane] : 0ull;
#pragma unroll
        for (int size = 2; size <= 64; size <<= 1) {
#pragma unroll
            for (int stride = size >> 1; stride > 0; stride >>= 1) {
                unsigned long long o = __shfl_xor((long long)key, stride, 64);
                bool takeMax = ((lane & size) == 0) == ((lane & stride) == 0);
                key = (takeMax == (key > o)) ? key : o;
            }
        }
        myg = 0.f; myj = 0;
        if (lane < KTOP) {
            myj = 2047 - (int)(key & 2047ull);
            myg = row[myj];
        }
    } else {
        // Fallback (rare): 16 rounds of full-row argmax with removal
        myg = 0.f; myj = 0;
        for (int k = 0; k < KTOP; k++) {
            float bv = -1.f, bs = 0.f; int bj = 0;
#pragma unroll
            for (int i = 0; i < 8; i++) {
                float4 v = p4[lane + 64 * i];
                int jb = 4 * (lane + 64 * i);
                { float a = fabsf(v.x); if (a > bv) { bv = a; bs = v.x; bj = jb; } }
                { float a = fabsf(v.y); if (a > bv) { bv = a; bs = v.y; bj = jb + 1; } }
                { float a = fabsf(v.z); if (a > bv) { bv = a; bs = v.z; bj = jb + 2; } }
                { float a = fabsf(v.w); if (a > bv) { bv = a; bs = v.w; bj = jb + 3; } }
            }
#pragma unroll
            for (int off2 = 32; off2 > 0; off2 >>= 1) {
                float ov = __shfl_xor(bv, off2, 64);
                float os = __shfl_xor(bs, off2, 64);
                int   oj = __shfl_xor(bj, off2, 64);
                if (ov > bv || (ov == bv && oj < bj)) { bv = ov; bs = os; bj = oj; }
            }
            if (lane == k) { myg = bs; myj = bj; }
            if (lane == 0) row[bj] = 0.f;
        }
    }
}
} // namespace

// ---------- state init: state_ws[b][s] = sign * softmax(|init_state|) ----------
__global__ void k_init_state(const float* __restrict__ init_state,
                             float* __restrict__ state_ws) {
    int b = blockIdx.x;
    int tid = threadIdx.x;
    __shared__ float red[256];
    float m = -1e30f;
    for (int s = tid; s < S; s += 256) m = fmaxf(m, fabsf(init_state[s]));
    red[tid] = m; __syncthreads();
    for (int off = 128; off > 0; off >>= 1) {
        if (tid < off) red[tid] = fmaxf(red[tid], red[tid + off]);
        __syncthreads();
    }
    m = red[0]; __syncthreads();
    float sum = 0.f;
    for (int s = tid; s < S; s += 256) sum += expf(fabsf(init_state[s]) - m);
    red[tid] = sum; __syncthreads();
    for (int off = 128; off > 0; off >>= 1) {
        if (tid < off) red[tid] += red[tid + off];
        __syncthreads();
    }
    float inv = 1.0f / red[0];
    for (int s = tid; s < S; s += 256) {
        float v = init_state[s];
        state_ws[(size_t)b * S + s] = signf(v) * expf(fabsf(v) - m) * inv;
    }
}

// ---------- val broadcast init: val1[b][s][:] = unit_norm(init_val[s]) ----------
__global__ void k_bcast(const float* __restrict__ init_val,
                        float* __restrict__ val1) {
    int wv = threadIdx.x >> 6;
    int lane = threadIdx.x & 63;
    int row = blockIdx.x * 4 + wv;        // row = b*S + s
    int s = row & (S - 1);
    const float4* src = (const float4*)(init_val + (size_t)s * D);
    float4 v0 = src[lane], v1 = src[lane + 64];
    float ss = v0.x * v0.x + v0.y * v0.y + v0.z * v0.z + v0.w * v0.w
             + v1.x * v1.x + v1.y * v1.y + v1.z * v1.z + v1.w * v1.w;
#pragma unroll
    for (int off = 32; off > 0; off >>= 1) ss += __shfl_xor(ss, off, 64);
    float sc = 1.0f / (sqrtf(ss) + 1e-6f);
    v0.x *= sc; v0.y *= sc; v0.z *= sc; v0.w *= sc;
    v1.x *= sc; v1.y *= sc; v1.z *= sc; v1.w *= sc;
    float4* dst = (float4*)(val1 + (size_t)row * D);
    dst[lane] = v0; dst[lane + 64] = v1;
}

// ---------- score stage: route scores -> per-wave topk -> bin lists ----------
__global__ void __launch_bounds__(256) k_score(const float* __restrict__ x,
                                               const float* __restrict__ route_a,
                                               const float* __restrict__ route_b,
                                               float* __restrict__ val1,
                                               float* __restrict__ state_ws,
                                               float* __restrict__ coef,
                                               int* __restrict__ bincount,
                                               int* __restrict__ binlist) {
    __shared__ __align__(16) float xs[NT][D];     // 8 KB
    __shared__ __align__(16) float sc[NT][S];     // 32 KB
    __shared__ __align__(16) float xr[NT][R];     // 1 KB
    __shared__ float red[256];
    __shared__ unsigned long long cand[NT][64];   // 2 KB

    int tid = threadIdx.x;
    int lane = tid & 63, wv = tid >> 6;
    int tb = blockIdx.x * NT;       // global token base (block never straddles b)
    int b = tb >> 11;               // T = 2048
    int t0 = tb & (T - 1);

    // load 4 x rows (vectorized)
    {
        const float4* xg = (const float4*)(x + (size_t)tb * D);
        float4* xls = (float4*)&xs[0][0];
        xls[tid] = xg[tid];
        xls[tid + 256] = xg[tid + 256];
    }
    __syncthreads();

    // xr = x . route_a  (b128 LDS reads)
    {
        int r = lane, grp = wv;
        float acc[NT] = {0.f, 0.f, 0.f, 0.f};
        for (int d0 = grp * 128; d0 < grp * 128 + 128; d0 += 4) {
            float a0 = route_a[(size_t)(d0 + 0) * R + r];
            float a1 = route_a[(size_t)(d0 + 1) * R + r];
            float a2 = route_a[(size_t)(d0 + 2) * R + r];
            float a3 = route_a[(size_t)(d0 + 3) * R + r];
#pragma unroll
            for (int tt = 0; tt < NT; tt++) {
                float4 xv = *(const float4*)&xs[tt][d0];
                acc[tt] += xv.x * a0 + xv.y * a1 + xv.z * a2 + xv.w * a3;
            }
        }
        for (int tt = 0; tt < NT; tt++) {
            red[tid] = acc[tt]; __syncthreads();
            if (tid < 64)
                xr[tt][tid] = red[tid] + red[tid + 64] + red[tid + 128] + red[tid + 192];
            __syncthreads();
        }
    }

    // scores = xr . route_b  (float4 over s)
    {
        const float4* rb4 = (const float4*)route_b;
#pragma unroll
        for (int i = 0; i < 2; i++) {
            int j4 = tid + 256 * i;
            float4 acc[NT];
#pragma unroll
            for (int tt = 0; tt < NT; tt++) acc[tt] = make_float4(0.f, 0.f, 0.f, 0.f);
            for (int r0 = 0; r0 < R; r0 += 4) {
                float4 xv[NT];
#pragma unroll
                for (int tt = 0; tt < NT; tt++) xv[tt] = *(const float4*)&xr[tt][r0];
#define SCORE_STEP(dr, comp)                                                   \
                {                                                              \
                    float4 bv = rb4[(size_t)(r0 + dr) * (S / 4) + j4];         \
                    _Pragma("unroll")                                          \
                    for (int tt = 0; tt < NT; tt++) {                          \
                        float c = xv[tt].comp;                                 \
                        acc[tt].x += c * bv.x; acc[tt].y += c * bv.y;          \
                        acc[tt].z += c * bv.z; acc[tt].w += c * bv.w;          \
                    }                                                          \
                }
                SCORE_STEP(0, x) SCORE_STEP(1, y) SCORE_STEP(2, z) SCORE_STEP(3, w)
#undef SCORE_STEP
            }
#pragma unroll
            for (int tt = 0; tt < NT; tt++)
                ((float4*)&sc[tt][0])[j4] = acc[tt];
        }
    }
    __syncthreads();

    // ---- per-wave from here: wave wv owns token tt = wv ----
    int tt = wv;
    int tloc = t0 + tt;
    int tglob = tb + tt;

    // x inverse norm (per wave, float4 LDS reads)
    float xinv;
    {
        const float4* xst = (const float4*)&xs[tt][0];
        float4 x0 = xst[lane], x1 = xst[lane + 64];
        float ss = x0.x * x0.x + x0.y * x0.y + x0.z * x0.z + x0.w * x0.w
                 + x1.x * x1.x + x1.y * x1.y + x1.z * x1.z + x1.w * x1.w;
#pragma unroll
        for (int off = 32; off > 0; off >>= 1) ss += __shfl_xor(ss, off, 64);
        xinv = 1.0f / (sqrtf(ss) + 1e-6f);
    }

    float myg; int myj;
    topk16_row(&sc[tt][0], &cand[wv][0], lane, myg, myj);

    // signed-abs-softmax over the 16 winners (lane k holds winner k)
    float m = __shfl(fabsf(myg), 0);
    float e = (lane < KTOP) ? expf(fabsf(myg) - m) : 0.f;
    float esum = e;
#pragma unroll
    for (int off = 8; off > 0; off >>= 1) esum += __shfl_xor(esum, off, 64);
    esum = __shfl(esum, 0);
    float w = signf(myg) * e / esum;
    float coefv = w * xinv;

    unsigned long long ovf = 0ull;
    int pos = 0;
    if (lane < KTOP) {
        float sp = (myg > 20.f) ? myg : log1pf(expf(myg));
        atomicAdd(&state_ws[(size_t)b * S + myj], sp);
        pos = atomicAdd(&bincount[(size_t)b * S + myj], 1);
        if (pos < CAP) {
            binlist[((size_t)b * S + myj) * CAP + pos] = (tloc << 4) | lane;
            coef[(size_t)tglob * KTOP + lane] = coefv;
        }
    }
    ovf = __ballot(lane < KTOP && pos >= CAP);
    while (ovf) {   // overflow fallback (essentially never)
        int src = __ffsll(ovf) - 1;
        int j = __shfl(myj, src);
        float c = __shfl(coefv, src);
        float* dst = val1 + ((size_t)b * S + j) * D;
#pragma unroll
        for (int i = 0; i < 8; i++)
            atomicAdd(&dst[lane + 64 * i], c * xs[tt][lane + 64 * i]);
        ovf &= ovf - 1;
    }
}

// ---------- accumulate bins: val1[row] = unit_norm(val1[row] + sum c*x) ----------
__global__ void __launch_bounds__(256) k_accum(const float* __restrict__ x,
                                               const float* __restrict__ coef,
                                               const int* __restrict__ bincount,
                                               const int* __restrict__ binlist,
                                               float* __restrict__ val1) {
    int lane = threadIdx.x & 63, wv = threadIdx.x >> 6;
    int row = blockIdx.x * 4 + wv;      // row = b*S + s
    int b = row >> 11;                  // S = 2048
    float4* vp4 = (float4*)(val1 + (size_t)row * D);
    float4 a0 = vp4[lane], a1 = vp4[lane + 64];
    int n = bincount[row]; if (n > CAP) n = CAP;
    const int* lp = binlist + (size_t)row * CAP;
    for (int base = 0; base < n; base += 64) {
        int mm = n - base; if (mm > 64) mm = 64;
        int ent = 0; float cc = 0.f;
        if (lane < mm) {
            ent = lp[base + lane];
            cc = coef[((size_t)b * T + (ent >> 4)) * KTOP + (ent & 15)];
        }
        for (int k = 0; k < mm; k++) {
            int e2 = __shfl(ent, k);
            float c = __shfl(cc, k);
            const float4* xp4 = (const float4*)(x + ((size_t)b * T + (e2 >> 4)) * D);
            float4 v0 = xp4[lane], v1 = xp4[lane + 64];
            a0.x += c * v0.x; a0.y += c * v0.y; a0.z += c * v0.z; a0.w += c * v0.w;
            a1.x += c * v1.x; a1.y += c * v1.y; a1.z += c * v1.z; a1.w += c * v1.w;
        }
    }
    float ss = a0.x * a0.x + a0.y * a0.y + a0.z * a0.z + a0.w * a0.w
             + a1.x * a1.x + a1.y * a1.y + a1.z * a1.z + a1.w * a1.w;
#pragma unroll
    for (int off = 32; off > 0; off >>= 1) ss += __shfl_xor(ss, off, 64);
    float sc = 1.0f / (sqrtf(ss) + 1e-6f);
    a0.x *= sc; a0.y *= sc; a0.z *= sc; a0.w *= sc;
    a1.x *= sc; a1.y *= sc; a1.z *= sc; a1.w *= sc;
    vp4[lane] = a0; vp4[lane + 64] = a1;
}

// ---------- state finalize: signed-abs-softmax -> out[...,0] ----------
__global__ void k_state_final(const float* __restrict__ state_ws,
                              float* __restrict__ out) {
    int b = blockIdx.x;
    int tid = threadIdx.x;
    __shared__ float red[256];
    const float* sp = state_ws + (size_t)b * S;
    float m = -1e30f;
    for (int s = tid; s < S; s += 256) m = fmaxf(m, fabsf(sp[s]));
    red[tid] = m; __syncthreads();
    for (int off = 128; off > 0; off >>= 1) {
        if (tid < off) red[tid] = fmaxf(red[tid], red[tid + off]);
        __syncthreads();
    }
    m = red[0]; __syncthreads();
    float sum = 0.f;
    for (int s = tid; s < S; s += 256) sum += expf(fabsf(sp[s]) - m);
    red[tid] = sum; __syncthreads();
    for (int off = 128; off > 0; off >>= 1) {
        if (tid < off) red[tid] += red[tid + off];
        __syncthreads();
    }
    float inv = 1.0f / red[0];
    for (int s = tid; s < S; s += 256) {
        float v = sp[s];
        out[((size_t)b * S + s) * (D + 1)] = signf(v) * expf(fabsf(v) - m) * inv;
    }
}

// ---------- q / kT projections ----------
__global__ void __launch_bounds__(256) k_qk(const float* __restrict__ val1,
                                            const float* __restrict__ pair_a,
                                            const float* __restrict__ pair_b,
                                            float* __restrict__ q,
                                            float* __restrict__ kkT) {
    __shared__ __align__(16) float vrow[NR][D];   // 32 KB
    __shared__ float redq[256];
    __shared__ float redk[256];
    int tid = threadIdx.x;
    int rowbase = blockIdx.x * NR;    // = b*S + sbase (never straddles b)
    int b = rowbase >> 11;
    int sbase = rowbase & (S - 1);
    {
        const float4* gv = (const float4*)(val1 + (size_t)rowbase * D);
        float4* lv = (float4*)&vrow[0][0];
        for (int i = tid; i < NR * D / 4; i += 256) lv[i] = gv[i];
    }
    __syncthreads();
    int r = tid & 63, grp = tid >> 6;
    float accq[NR], acck[NR];
#pragma unroll
    for (int rr = 0; rr < NR; rr++) { accq[rr] = 0.f; acck[rr] = 0.f; }
    for (int d0 = grp * 128; d0 < grp * 128 + 128; d0 += 4) {
#pragma unroll
        for (int dd = 0; dd < 4; dd++) {
            float a  = pair_a[(size_t)(d0 + dd) * R + r];
            float bb = pair_b[(size_t)(d0 + dd) * R + r];
#pragma unroll
            for (int rr = 0; rr < NR; rr++) {
                float v = vrow[rr][d0 + dd];
                accq[rr] += v * a;
                acck[rr] += v * bb;
            }
        }
    }
    for (int rr = 0; rr < NR; rr++) {
        redq[tid] = accq[rr]; redk[tid] = acck[rr];
        __syncthreads();
        if (tid < 64) {
            float qv = redq[tid] + redq[tid + 64] + redq[tid + 128] + redq[tid + 192];
            float kv = redk[tid] + redk[tid + 64] + redk[tid + 128] + redk[tid + 192];
            q[(size_t)(rowbase + rr) * R + tid] = qv;
            kkT[((size_t)b * R + tid) * S + (sbase + rr)] = kv;
        }
        __syncthreads();
    }
}

// ---------- pscore: p = q.kT (float4), per-wave topk -> eidx/ew ----------
__global__ void __launch_bounds__(256) k_pscore(const float* __restrict__ q,
                                                const float* __restrict__ kkT,
                                                int* __restrict__ eidx,
                                                float* __restrict__ ew_g) {
    __shared__ __align__(16) float prow[NI][S];   // 32 KB
    __shared__ __align__(16) float qrow[NI][R];
    __shared__ unsigned long long cand[NI][64];   // 2 KB

    int tid = threadIdx.x;
    int lane = tid & 63, wv = tid >> 6;
    int ibase = blockIdx.x * NI;     // global row base (never straddles b)
    int b = ibase >> 11;             // S = 2048

    {
        int rr = tid >> 6, r = tid & 63;
        qrow[rr][r] = q[(size_t)(ibase + rr) * R + r];
    }
    __syncthreads();

    // p rows (float4 over j; kkT slice reused by 4 rows)
    {
        const float4* kk4 = (const float4*)(kkT + (size_t)b * R * S);
#pragma unroll
        for (int i = 0; i < 2; i++) {
            int j4 = tid + 256 * i;
            float4 acc[NI];
#pragma unroll
            for (int rr = 0; rr < NI; rr++) acc[rr] = make_float4(0.f, 0.f, 0.f, 0.f);
            for (int r0 = 0; r0 < R; r0 += 4) {
                float4 qv[NI];
#pragma unroll
                for (int rr = 0; rr < NI; rr++) qv[rr] = *(const float4*)&qrow[rr][r0];
#define P_STEP(dr, comp)                                                       \
                {                                                              \
                    float4 kv = kk4[(size_t)(r0 + dr) * (S / 4) + j4];         \
                    _Pragma("unroll")                                          \
                    for (int rr = 0; rr < NI; rr++) {                          \
                        float c = qv[rr].comp;                                 \
                        acc[rr].x += c * kv.x; acc[rr].y += c * kv.y;          \
                        acc[rr].z += c * kv.z; acc[rr].w += c * kv.w;          \
                    }                                                          \
                }
                P_STEP(0, x) P_STEP(1, y) P_STEP(2, z) P_STEP(3, w)
#undef P_STEP
            }
#pragma unroll
            for (int rr = 0; rr < NI; rr++)
                ((float4*)&prow[rr][0])[j4] = acc[rr];
        }
    }
    __syncthreads();

    // ---- per-wave topk on row ibase + wv ----
    int row = ibase + wv;
    float myg; int myj;
    topk16_row(&prow[wv][0], &cand[wv][0], lane, myg, myj);

    float m = __shfl(fabsf(myg), 0);
    float e = (lane < KTOP) ? expf(fabsf(myg) - m) : 0.f;
    float esum = e;
#pragma unroll
    for (int off = 8; off > 0; off >>= 1) esum += __shfl_xor(esum, off, 64);
    esum = __shfl(esum, 0);
    float myw = signf(myg) * e / esum;

    if (lane < KTOP) {
        eidx[(size_t)row * KTOP + lane] = myj;
        ew_g[(size_t)row * KTOP + lane] = myw;
    }
}

// ---------- mix: gather neighbors, residual add, unit-norm, out[...,1:] ----------
__global__ void __launch_bounds__(256) k_mix(const int* __restrict__ eidx,
                                             const float* __restrict__ ew_g,
                                             const float* __restrict__ val1,
                                             float* __restrict__ out) {
    int lane = threadIdx.x & 63, wv = threadIdx.x >> 6;
    int row = blockIdx.x * 4 + wv;
    int b = row >> 11;

    int e_i = 0; float e_w = 0.f;
    if (lane < KTOP) {
        e_i = eidx[(size_t)row * KTOP + lane];
        e_w = ew_g[(size_t)row * KTOP + lane];
    }

    const float4* self4 = (const float4*)(val1 + (size_t)row * D);
    float4 a0 = self4[lane], a1 = self4[lane + 64];
#pragma unroll
    for (int k = 0; k < KTOP; k++) {
        int j = __shfl(e_i, k);
        float w = __shfl(e_w, k);
        const float4* nb4 = (const float4*)(val1 + ((size_t)b * S + j) * D);
        float4 v0 = nb4[lane], v1 = nb4[lane + 64];
        a0.x += w * v0.x; a0.y += w * v0.y; a0.z += w * v0.z; a0.w += w * v0.w;
        a1.x += w * v1.x; a1.y += w * v1.y; a1.z += w * v1.z; a1.w += w * v1.w;
    }
    float ss = a0.x * a0.x + a0.y * a0.y + a0.z * a0.z + a0.w * a0.w
             + a1.x * a1.x + a1.y * a1.y + a1.z * a1.z + a1.w * a1.w;
#pragma unroll
    for (int off = 32; off > 0; off >>= 1) ss += __shfl_xor(ss, off, 64);
    float sc = 1.0f / (sqrtf(ss) + 1e-6f);
    float* op = out + (size_t)row * (D + 1) + 1;
    int d0 = 4 * lane;
    op[d0 + 0] = a0.x * sc; op[d0 + 1] = a0.y * sc;
    op[d0 + 2] = a0.z * sc; op[d0 + 3] = a0.w * sc;
    op[256 + d0 + 0] = a1.x * sc; op[256 + d0 + 1] = a1.y * sc;
    op[256 + d0 + 2] = a1.z * sc; op[256 + d0 + 3] = a1.w * sc;
}

extern "C" void kernel_launch(void* const* d_in, const int* in_sizes, int n_in,
                              void* d_out, int out_size, void* d_ws, size_t ws_size,
                              hipStream_t stream) {
    (void)in_sizes; (void)n_in; (void)out_size; (void)ws_size;
    const float* x          = (const float*)d_in[0];
    const float* init_state = (const float*)d_in[1];
    const float* init_val   = (const float*)d_in[2];
    const float* route_a    = (const float*)d_in[3];
    const float* route_b    = (const float*)d_in[4];
    const float* pair_a     = (const float*)d_in[5];
    const float* pair_b     = (const float*)d_in[6];
    float* out = (float*)d_out;

    float* ws       = (float*)d_ws;
    float* val1     = ws;                             // B*S*D
    float* q        = val1 + (size_t)B * S * D;       // B*S*R
    float* kkT      = q    + (size_t)B * S * R;       // B*R*S
    float* state_ws = kkT  + (size_t)B * R * S;       // B*S
    float* coef     = state_ws + (size_t)B * S;       // B*T*K
    int*   bincount = (int*)(coef + (size_t)B * T * KTOP);   // B*S
    int*   binlist  = bincount + (size_t)B * S;              // B*S*CAP
    // eidx/ew reuse binlist space (binlist dead after k_accum)
    int*   eidx     = binlist;                               // B*S*K
    float* ew       = (float*)(binlist + (size_t)B * S * KTOP);  // B*S*K

    hipMemsetAsync(bincount, 0, (size_t)B * S * sizeof(int), stream);
    hipLaunchKernelGGL(k_init_state, dim3(B), dim3(256), 0, stream, init_state, state_ws);
    hipLaunchKernelGGL(k_bcast, dim3(B * S / 4), dim3(256), 0, stream, init_val, val1);
    hipLaunchKernelGGL(k_score, dim3(B * T / NT), dim3(256), 0, stream,
                       x, route_a, route_b, val1, state_ws, coef, bincount, binlist);
    hipLaunchKernelGGL(k_state_final, dim3(B), dim3(256), 0, stream, state_ws, out);
    hipLaunchKernelGGL(k_accum, dim3(B * S / 4), dim3(256), 0, stream,
                       x, coef, bincount, binlist, val1);
    hipLaunchKernelGGL(k_qk, dim3(B * S / NR), dim3(256), 0, stream,
                       val1, pair_a, pair_b, q, kkT);
    hipLaunchKernelGGL(k_pscore, dim3(B * S / NI), dim3(256), 0, stream,
                       q, kkT, eidx, ew);
    hipLaunchKernelGGL(k_mix, dim3(B * S / 4), dim3(256), 0, stream,
                       eidx, ew, val1, out);
}